// Round 10
// baseline (172.319 us; speedup 1.0000x reference)
//
#include <hip/hip_runtime.h>

typedef __bf16   bf16x8 __attribute__((ext_vector_type(8)));
typedef float    f32x4  __attribute__((ext_vector_type(4)));
typedef float    f32x2  __attribute__((ext_vector_type(2)));
typedef uint32_t u32x4  __attribute__((ext_vector_type(4)));

constexpr int N_ = 16384;
constexpr int D_ = 16;
constexpr int P_ = 8;
constexpr int H_ = 128;
constexpr int M_ = 50;

// prologue-only pack (round-half-up; matches all passing rounds)
__device__ __forceinline__ uint32_t pk_bf16(float a, float b) {
    uint32_t ua = __builtin_bit_cast(uint32_t, a) + 0x8000u;
    uint32_t ub = __builtin_bit_cast(uint32_t, b) + 0x8000u;
    return __builtin_amdgcn_perm(ub, ua, 0x07060302u);   // low=a, high=b
}
// in-loop pack (RNE; validated R7/R8/R11/R12)
__device__ __forceinline__ uint32_t cvtpk(float a, float b) {
    uint32_t r;
    asm("v_cvt_pk_bf16_f32 %0, %1, %2" : "=v"(r) : "v"(a), "v"(b));
    return r;
}
__device__ __forceinline__ uint32_t cvtpk_relu(float a, float b) {
    return cvtpk(fmaxf(a, 0.0f), fmaxf(b, 0.0f));
}

// volatile 16B LDS reads: cannot be promoted across iterations (the R7/R9
// spill cause); compiler still inserts correct lgkmcnt (no rule-#18 hazard).
// R12-proven (VGPR 120, zero spill).
__device__ __forceinline__ bf16x8 lds_ldv8(const void* p) {
    u32x4 v = *(volatile const u32x4*)p;
    return __builtin_bit_cast(bf16x8, v);
}
__device__ __forceinline__ f32x4 lds_ldvf(const void* p) {
    u32x4 v = *(volatile const u32x4*)p;
    return __builtin_bit_cast(f32x4, v);
}

// R13: time-split 2 waves/SIMD, ZERO in-loop barriers, W2 register-resident,
// W1/W3/b2 streamed from LDS via RING-PREFETCHED register buffers whose
// lookahead wraps across steps (weights identical every step, so ring index
// (i+k)&mask prefetches the NEXT step's fragment a full layer early).
// Evidence base: R4 proved cross-wave MFMA co-issue works (2-wave pipe-busy
// == 1-wave) but lockstep barriers ate it; R12 proved no-spill 2-wave is
// achievable but put 32 volatile LDS reads at ~1-ct lookahead INSIDE the L2
// chain (latency on the critical path, zero overlap). R13 removes both:
// every in-loop LDS read is issued >=4 MFMAs (~100-500 cyc) before its use.
// Ledger: w2f 128 + rings (w1 16, w3 8, b2 8) + b3r 4 + h1b/h2b 32 + rolling
// accs ~12 + state ~30 ~= 240 unified regs < 256.
// GATES: WRITE_SIZE ~1.1 MB & Occ ~25% (resident); then dur < 45 us or the
// occupancy direction is declared closed and we revert to R8.
__global__ __launch_bounds__(128, 2)
void sde_fused(const float* __restrict__ X0,
               const float* __restrict__ V0,
               const float* __restrict__ Yobs,
               const float* __restrict__ noise,
               const float* __restrict__ W1, const float* __restrict__ b1,
               const float* __restrict__ W2, const float* __restrict__ b2,
               const float* __restrict__ W3, const float* __restrict__ b3,
               float* __restrict__ out)
{
    const int tid  = threadIdx.x;
    const int lane = tid & 63;
    const int half = tid >> 6;           // 0: steps 0..24, 1: steps 25..49
    const int n    = lane & 15;
    const int q    = lane >> 4;
    const int gr   = blockIdx.x * 16 + n;

    const float dt   = 0.02f;
    const float sqdt = 0.1414213562373095f;

    // LDS: w1 frags [8][64]x16B @0 ; w3 frags [4][64]x16B @8192 ;
    //      b2 [128]f @12288 ; vpart [16]f @12800
    __shared__ __align__(16) unsigned char smem[12864];

    // ---- prologue: wave 0 stages LDS operands ----
    if (half == 0) {
#pragma unroll
        for (int ct = 0; ct < 8; ++ct) {
            u32x4 u;
            u[0] = pk_bf16(W1[(1 + q * 4 + 0) * H_ + ct * 16 + n],
                           W1[(1 + q * 4 + 1) * H_ + ct * 16 + n]);
            u[1] = pk_bf16(W1[(1 + q * 4 + 2) * H_ + ct * 16 + n],
                           W1[(1 + q * 4 + 3) * H_ + ct * 16 + n]);
            u[2] = pk_bf16(W1[(17 + q * 2 + 0) * H_ + ct * 16 + n],
                           W1[(17 + q * 2 + 1) * H_ + ct * 16 + n]);
            u[3] = (q == 0) ? pk_bf16(b1[ct * 16 + n], W1[ct * 16 + n]) : 0u;
            *(u32x4*)(smem + ct * 1024 + lane * 16) = u;
            __builtin_amdgcn_sched_barrier(0);
        }
#pragma unroll
        for (int kt = 0; kt < 4; ++kt) {
            u32x4 u;
#pragma unroll
            for (int w = 0; w < 4; ++w) {
                int h0 = (kt * 2 + (w >> 1)) * 16 + q * 4 + (w & 1) * 2;
                u[w] = pk_bf16(W3[h0 * D_ + n], W3[(h0 + 1) * D_ + n]);
            }
            *(u32x4*)(smem + 8192 + kt * 1024 + lane * 16) = u;
            __builtin_amdgcn_sched_barrier(0);
        }
        if (lane < 32) *(f32x4*)(smem + 12288 + lane * 16) = *(const f32x4*)&b2[lane * 4];
    }

    // ---- W2: register-resident in both waves (the one true hog) ----
    bf16x8 w2f[8][4];
#pragma unroll
    for (int ct = 0; ct < 8; ++ct) {
#pragma unroll
        for (int kt = 0; kt < 4; ++kt) {
            u32x4 u;
#pragma unroll
            for (int w = 0; w < 4; ++w) {
                int h0 = (kt * 2 + (w >> 1)) * 16 + q * 4 + (w & 1) * 2;
                u[w] = pk_bf16(W2[h0 * H_ + ct * 16 + n],
                               W2[(h0 + 1) * H_ + ct * 16 + n]);
            }
            w2f[ct][kt] = __builtin_bit_cast(bf16x8, u);
        }
        __builtin_amdgcn_sched_barrier(0);   // cap prologue register spike
    }

    f32x4 b3r = *(const f32x4*)&b3[q * 4];

    __syncthreads();   // LDS weights ready (only barrier before the end)

    // ---- state ----
    f32x4 x = *(const f32x4*)&X0[gr * D_ + q * 4];
    f32x2 y2 = *(const f32x2*)&Yobs[gr * P_ + q * 2];
    const uint32_t yw = pk_bf16(y2[0], y2[1]);
    const float* npb = noise + (size_t)gr * D_ + q * 4;

    // ---- wave 1: bit-exact X-recurrence replay through steps 0..24 ----
    if (half == 1) {
#pragma unroll 2
        for (int m = 0; m < 25; ++m) {
            f32x4 e = *(const f32x4*)(npb + (size_t)m * N_ * D_);
#pragma unroll
            for (int r = 0; r < 4; ++r)
                x[r] = fmaf(x[r], 0.98f, sqdt * e[r]);
        }
    }

    const int s0 = half * 25;
    float t = half ? 0.5f : 0.0f;        // 25*dt == 0.5 (proven handoff)
    f32x4 e0 = *(const f32x4*)(npb + (size_t)s0 * N_ * D_);
    float vacc = 0.0f;

    const uint32_t lofs = (uint32_t)lane * 16u;
    const uint32_t qofs = (uint32_t)q * 16u;

    // ---- ring buffers (prologue fill; wrap indices reload for next step) ----
    bf16x8 w1buf[4];
#pragma unroll
    for (int k = 0; k < 4; ++k) w1buf[k] = lds_ldv8(smem + k * 1024 + lofs);
    bf16x8 w3buf[2];
    w3buf[0] = lds_ldv8(smem + 8192 + 0 * 1024 + lofs);
    w3buf[1] = lds_ldv8(smem + 8192 + 1 * 1024 + lofs);
    f32x4 b2buf[2];
    b2buf[0] = lds_ldvf(smem + 12288 + 0 * 64 + qofs);
    b2buf[1] = lds_ldvf(smem + 12288 + 1 * 64 + qofs);

#pragma unroll 1
    for (int i = 0; i < 25; ++i) {
        const int m  = s0 + i;
        const int mn = (m + 1 < M_) ? (m + 1) : (M_ - 1);
        f32x4 e1 = *(const f32x4*)(npb + (size_t)mn * N_ * D_);

        // ---- layer 1 B fragment ----
        u32x4 au;
        au[0] = cvtpk(x[0], x[1]);
        au[1] = cvtpk(x[2], x[3]);
        au[2] = yw;
        au[3] = (q == 0) ? cvtpk(1.0f, t) : 0u;
        bf16x8 a0 = __builtin_bit_cast(bf16x8, au);

        // ---- layer 1: ring-4 w1; refill (ct+4)&7 -> 4-MFMA lookahead,
        //      wraps into the next step's frags at ct>=4 ----
        bf16x8 h1b[4];
        f32x4 hodd;
#pragma unroll
        for (int ct = 0; ct < 8; ++ct) {
            const int b = ct & 3;
            f32x4 h = __builtin_amdgcn_mfma_f32_16x16x32_bf16(
                w1buf[b], a0, (f32x4){0.f, 0.f, 0.f, 0.f}, 0, 0, 0);
            w1buf[b] = lds_ldv8(smem + ((ct + 4) & 7) * 1024 + lofs);
            if ((ct & 1) == 0) {
                hodd = h;
            } else {
                u32x4 u;
                u[0] = cvtpk_relu(hodd[0], hodd[1]);
                u[1] = cvtpk_relu(hodd[2], hodd[3]);
                u[2] = cvtpk_relu(h[0], h[1]);
                u[3] = cvtpk_relu(h[2], h[3]);
                h1b[ct >> 1] = __builtin_bit_cast(bf16x8, u);
            }
        }

        // ---- layer 2: ct-pairs; C-in from b2 ring-2 (refill 1 pair = 8
        //      MFMAs ahead, wraps to next step at ctp 3) ----
        bf16x8 h2b[4];
#pragma unroll
        for (int ctp = 0; ctp < 4; ++ctp) {
            f32x4 c0 = b2buf[0];
            f32x4 c1 = b2buf[1];
            b2buf[0] = lds_ldvf(smem + 12288 + ((2 * ctp + 2) & 7) * 64 + qofs);
            b2buf[1] = lds_ldvf(smem + 12288 + ((2 * ctp + 3) & 7) * 64 + qofs);
#pragma unroll
            for (int kt = 0; kt < 4; ++kt)
                c0 = __builtin_amdgcn_mfma_f32_16x16x32_bf16(
                    w2f[2 * ctp][kt], h1b[kt], c0, 0, 0, 0);
#pragma unroll
            for (int kt = 0; kt < 4; ++kt)
                c1 = __builtin_amdgcn_mfma_f32_16x16x32_bf16(
                    w2f[2 * ctp + 1][kt], h1b[kt], c1, 0, 0, 0);
            u32x4 u;
            u[0] = cvtpk_relu(c0[0], c0[1]);
            u[1] = cvtpk_relu(c0[2], c0[3]);
            u[2] = cvtpk_relu(c1[0], c1[1]);
            u[3] = cvtpk_relu(c1[2], c1[3]);
            h2b[ctp] = __builtin_bit_cast(bf16x8, u);
        }

        // ---- layer 3: ring-2 w3; refills wrap to next step ----
        f32x4 za = __builtin_amdgcn_mfma_f32_16x16x32_bf16(w3buf[0], h2b[0], b3r, 0, 0, 0);
        w3buf[0] = lds_ldv8(smem + 8192 + 2 * 1024 + lofs);
        za = __builtin_amdgcn_mfma_f32_16x16x32_bf16(w3buf[1], h2b[1], za, 0, 0, 0);
        w3buf[1] = lds_ldv8(smem + 8192 + 3 * 1024 + lofs);
        f32x4 zb = __builtin_amdgcn_mfma_f32_16x16x32_bf16(
            w3buf[0], h2b[2], (f32x4){0.f, 0.f, 0.f, 0.f}, 0, 0, 0);
        w3buf[0] = lds_ldv8(smem + 8192 + 0 * 1024 + lofs);
        zb = __builtin_amdgcn_mfma_f32_16x16x32_bf16(w3buf[1], h2b[3], zb, 0, 0, 0);
        w3buf[1] = lds_ldv8(smem + 8192 + 1 * 1024 + lofs);

        // ---- V partial + X update ----
#pragma unroll
        for (int r = 0; r < 4; ++r) {
            float z  = za[r] + zb[r];
            float wn = sqdt * e0[r];
            vacc = fmaf(z, wn, fmaf(0.01f * z, z, vacc));   // z*wn + dt/2*z^2
            x[r] = fmaf(x[r], 0.98f, wn);                   // (1-dt)*x + wn
        }

        e0 = e1;
        t += dt;
    }

    // ---- V reduction across the 4 q-groups within each wave ----
    float part = vacc;
    part += __shfl_xor(part, 16);
    part += __shfl_xor(part, 32);

    // ---- combine the two time-halves ----
    if (half == 0 && q == 0) *(float*)(smem + 12800 + n * 4) = part;
    __syncthreads();
    if (half == 1) {
        *(f32x4*)&out[gr * D_ + q * 4] = x;                 // final X (step 50)
        if (q == 0)
            out[N_ * D_ + gr] = V0[gr] + *(const float*)(smem + 12800 + n * 4) + part;
    }
}

extern "C" void kernel_launch(void* const* d_in, const int* in_sizes, int n_in,
                              void* d_out, int out_size, void* d_ws, size_t ws_size,
                              hipStream_t stream)
{
    const float* X0 = (const float*)d_in[0];
    const float* V0 = (const float*)d_in[1];
    const float* Y  = (const float*)d_in[2];
    const float* nz = (const float*)d_in[3];
    const float* W1 = (const float*)d_in[4];
    const float* b1 = (const float*)d_in[5];
    const float* W2 = (const float*)d_in[6];
    const float* b2 = (const float*)d_in[7];
    const float* W3 = (const float*)d_in[8];
    const float* b3 = (const float*)d_in[9];
    float* out = (float*)d_out;

    sde_fused<<<N_ / 16, 128, 0, stream>>>(X0, V0, Y, nz, W1, b1, W2, b2, W3, b3, out);
}

// Round 11
// 156.197 us; speedup vs baseline: 1.1032x; 1.1032x over previous
//
#include <hip/hip_runtime.h>

typedef __bf16   bf16x8 __attribute__((ext_vector_type(8)));
typedef float    f32x4  __attribute__((ext_vector_type(4)));
typedef float    f32x16 __attribute__((ext_vector_type(16)));
typedef uint32_t u32x4  __attribute__((ext_vector_type(4)));

constexpr int N_ = 16384;
constexpr int D_ = 16;
constexpr int P_ = 8;
constexpr int H_ = 128;
constexpr int M_ = 50;

// prologue-only pack (round-half-up; matches all passing rounds)
__device__ __forceinline__ uint32_t pk_bf16(float a, float b) {
    uint32_t ua = __builtin_bit_cast(uint32_t, a) + 0x8000u;
    uint32_t ub = __builtin_bit_cast(uint32_t, b) + 0x8000u;
    return __builtin_amdgcn_perm(ub, ua, 0x07060302u);   // low=a, high=b
}
// in-loop pack (RNE; validated R7/R8/R11/R12)
__device__ __forceinline__ uint32_t cvtpk(float a, float b) {
    uint32_t r;
    asm("v_cvt_pk_bf16_f32 %0, %1, %2" : "=v"(r) : "v"(a), "v"(b));
    return r;
}
__device__ __forceinline__ uint32_t cvtpk_relu(float a, float b) {
    return cvtpk(fmaxf(a, 0.0f), fmaxf(b, 0.0f));
}

// R14: 32x32x16 MFMA shape, 32 particles/wave — attacks the measured
// constraint (per-wave MFMA ISSUE CADENCE ~60-84 cyc/instr, invariant to
// dependence/VALU/co-residency across R0/R8/R10/R11/R12). 52 MFMA per 32
// particles vs R0's 44 per 16 -> 1.7x fewer issues per particle.
// Layouts (by proven 16x16 analogy + measured C/D):
//   A[m=lane&31][k=8*(lane>>5)+j], B[k=8*(lane>>5)+j][n=lane&31],
//   C/D: col=lane&31, row=(reg&3)+8*(reg>>2)+4*(lane>>5).
// K-permutation pi(kt,hi,j)=kt*16+(j&3)+8*(j>>2)+4*hi baked into A-frags so
// each layer's C/D regs ARE the next layer's B-frag lane-locally:
//   B-frag(kt) = cvtpk_relu(acc[kt>>1] regs 8*(kt&1)..+7). Zero cross-lane.
// X-dims split per lane (hi half) to match C/D halves: lane(n,hi) owns dims
// {0..3,8..11}+4hi -> noise/V-dot/X-update all lane-local; V combined by one
// shfl_xor(32).  b2 enters via a bias K-slot (A=b2 at k=0, B=1), b3 as C-in.
// Chip fill: proven time-split (2 waves/block, steps 0-24/25-49, bit-exact
// X replay, zero in-loop barriers). 512 blocks x 128 thr = 1 wave/SIMD at
// ~370 regs (1-wave budget 512: no spill).
__global__ __launch_bounds__(128, 1)
void sde_fused(const float* __restrict__ X0,
               const float* __restrict__ V0,
               const float* __restrict__ Yobs,
               const float* __restrict__ noise,
               const float* __restrict__ W1, const float* __restrict__ b1,
               const float* __restrict__ W2, const float* __restrict__ b2,
               const float* __restrict__ W3, const float* __restrict__ b3,
               float* __restrict__ out)
{
    const int tid  = threadIdx.x;
    const int lane = tid & 63;
    const int half = tid >> 6;          // 0: steps 0..24, 1: steps 25..49
    const int n    = lane & 31;         // particle within block
    const int hi   = lane >> 5;         // K/C-D half
    const int gr   = blockIdx.x * 32 + n;

    const float dt   = 0.02f;
    const float sqdt = 0.1414213562373095f;

    const f32x16 Z16 = {0.f,0.f,0.f,0.f,0.f,0.f,0.f,0.f,
                        0.f,0.f,0.f,0.f,0.f,0.f,0.f,0.f};

    // ---- L1 A-frags: 4 M-tiles x 2 K-tiles ----
    // K-tile0 x-dims: (j&3)+8*(j>>2)+4hi -> W1 rows 1+that.
    // K-tile1: hi=0 -> Y rows 17..24 ; hi=1 -> j0:t-row(W1[0]), j1:b1, rest 0.
    bf16x8 a1f[4][2];
#pragma unroll
    for (int mt = 0; mt < 4; ++mt) {
        const int col = mt * 32 + n;
        u32x4 u;
        u[0] = pk_bf16(W1[(1 + 4*hi) * H_ + col],  W1[(2 + 4*hi) * H_ + col]);
        u[1] = pk_bf16(W1[(3 + 4*hi) * H_ + col],  W1[(4 + 4*hi) * H_ + col]);
        u[2] = pk_bf16(W1[(9 + 4*hi) * H_ + col],  W1[(10 + 4*hi) * H_ + col]);
        u[3] = pk_bf16(W1[(11 + 4*hi) * H_ + col], W1[(12 + 4*hi) * H_ + col]);
        a1f[mt][0] = __builtin_bit_cast(bf16x8, u);
        u32x4 v;
        v[0] = hi ? pk_bf16(W1[0 * H_ + col], b1[col])
                  : pk_bf16(W1[17 * H_ + col], W1[18 * H_ + col]);
        v[1] = hi ? 0u : pk_bf16(W1[19 * H_ + col], W1[20 * H_ + col]);
        v[2] = hi ? 0u : pk_bf16(W1[21 * H_ + col], W1[22 * H_ + col]);
        v[3] = hi ? 0u : pk_bf16(W1[23 * H_ + col], W1[24 * H_ + col]);
        a1f[mt][1] = __builtin_bit_cast(bf16x8, v);
    }

    // ---- L2 A-frags: 4 M-tiles x 8 K-tiles + bias tile ----
    bf16x8 a2f[4][8], a2b[4];
#pragma unroll
    for (int mt = 0; mt < 4; ++mt) {
        const int col = mt * 32 + n;
#pragma unroll
        for (int kt = 0; kt < 8; ++kt) {
            const int r0 = kt * 16 + 4 * hi;
            u32x4 u;
            u[0] = pk_bf16(W2[(r0 + 0) * H_ + col],  W2[(r0 + 1) * H_ + col]);
            u[1] = pk_bf16(W2[(r0 + 2) * H_ + col],  W2[(r0 + 3) * H_ + col]);
            u[2] = pk_bf16(W2[(r0 + 8) * H_ + col],  W2[(r0 + 9) * H_ + col]);
            u[3] = pk_bf16(W2[(r0 + 10) * H_ + col], W2[(r0 + 11) * H_ + col]);
            a2f[mt][kt] = __builtin_bit_cast(bf16x8, u);
        }
        u32x4 ub;
        ub[0] = hi ? 0u : pk_bf16(b2[col], 0.0f);   // k-slot 0 = b2[m]
        ub[1] = 0u; ub[2] = 0u; ub[3] = 0u;
        a2b[mt] = __builtin_bit_cast(bf16x8, ub);
    }

    // ---- L3 A-frags: 1 M-tile (rows>=16 zero) x 8 K-tiles ----
    bf16x8 a3f[8];
    const bool mv = (n < 16);
#pragma unroll
    for (int kt = 0; kt < 8; ++kt) {
        const int r0 = kt * 16 + 4 * hi;
        float f0 = mv ? W3[(r0 + 0) * D_ + n] : 0.0f;
        float f1 = mv ? W3[(r0 + 1) * D_ + n] : 0.0f;
        float f2 = mv ? W3[(r0 + 2) * D_ + n] : 0.0f;
        float f3 = mv ? W3[(r0 + 3) * D_ + n] : 0.0f;
        float f4 = mv ? W3[(r0 + 8) * D_ + n] : 0.0f;
        float f5 = mv ? W3[(r0 + 9) * D_ + n] : 0.0f;
        float f6 = mv ? W3[(r0 + 10) * D_ + n] : 0.0f;
        float f7 = mv ? W3[(r0 + 11) * D_ + n] : 0.0f;
        u32x4 u;
        u[0] = pk_bf16(f0, f1);
        u[1] = pk_bf16(f2, f3);
        u[2] = pk_bf16(f4, f5);
        u[3] = pk_bf16(f6, f7);
        a3f[kt] = __builtin_bit_cast(bf16x8, u);
    }

    // ---- b3 as L3 C-in (regs 0..7 carry rows<16; 8..15 padded rows) ----
    f32x16 b3c = Z16;
#pragma unroll
    for (int r = 0; r < 8; ++r) b3c[r] = b3[(r & 3) + 8 * (r >> 2) + 4 * hi];

    // ---- bias B-frag: B[k=0][n]=1, else 0 ----
    u32x4 fbu;
    fbu[0] = hi ? 0u : pk_bf16(1.0f, 0.0f);
    fbu[1] = 0u; fbu[2] = 0u; fbu[3] = 0u;
    const bf16x8 fbias = __builtin_bit_cast(bf16x8, fbu);

    // ---- constant Y words (consumed by hi=0 lanes in the L1 K-tile1 frag) ----
    f32x4 y0 = *(const f32x4*)&Yobs[gr * P_];
    f32x4 y1 = *(const f32x4*)&Yobs[gr * P_ + 4];
    const uint32_t yw0 = pk_bf16(y0[0], y0[1]);
    const uint32_t yw1 = pk_bf16(y0[2], y0[3]);
    const uint32_t yw2 = pk_bf16(y1[0], y1[1]);
    const uint32_t yw3 = pk_bf16(y1[2], y1[3]);

    // ---- state: lane(n,hi) owns x/e dims {0..3}+4hi (xA) and {8..11}+4hi (xB) ----
    f32x4 xA = *(const f32x4*)&X0[gr * D_ + 4 * hi];
    f32x4 xB = *(const f32x4*)&X0[gr * D_ + 8 + 4 * hi];
    const float* npb = noise + (size_t)gr * D_ + 4 * hi;

    // ---- wave 1: bit-exact X-recurrence replay through steps 0..24 ----
    if (half == 1) {
#pragma unroll 2
        for (int m = 0; m < 25; ++m) {
            f32x4 eA = *(const f32x4*)(npb + (size_t)m * N_ * D_);
            f32x4 eB = *(const f32x4*)(npb + (size_t)m * N_ * D_ + 8);
#pragma unroll
            for (int r = 0; r < 4; ++r) {
                xA[r] = fmaf(xA[r], 0.98f, sqdt * eA[r]);
                xB[r] = fmaf(xB[r], 0.98f, sqdt * eB[r]);
            }
        }
    }

    const int s0 = half * 25;
    float t = half ? 0.5f : 0.0f;        // 25*dt == 0.5 (proven handoff)
    f32x4 eA0 = *(const f32x4*)(npb + (size_t)s0 * N_ * D_);
    f32x4 eB0 = *(const f32x4*)(npb + (size_t)s0 * N_ * D_ + 8);
    float vacc = 0.0f;

#pragma unroll 1
    for (int i = 0; i < 25; ++i) {
        const int m  = s0 + i;
        const int mn = (m + 1 < M_) ? (m + 1) : (M_ - 1);
        f32x4 eA1 = *(const f32x4*)(npb + (size_t)mn * N_ * D_);
        f32x4 eB1 = *(const f32x4*)(npb + (size_t)mn * N_ * D_ + 8);

        // ---- L1 B-frags ----
        u32x4 g0u;
        g0u[0] = cvtpk(xA[0], xA[1]);
        g0u[1] = cvtpk(xA[2], xA[3]);
        g0u[2] = cvtpk(xB[0], xB[1]);
        g0u[3] = cvtpk(xB[2], xB[3]);
        bf16x8 g0 = __builtin_bit_cast(bf16x8, g0u);
        u32x4 g1u;
        g1u[0] = hi ? cvtpk(t, 1.0f) : yw0;   // j0: t-row, j1: b1 (value 1)
        g1u[1] = hi ? 0u : yw1;
        g1u[2] = hi ? 0u : yw2;
        g1u[3] = hi ? 0u : yw3;
        bf16x8 g1 = __builtin_bit_cast(bf16x8, g1u);

        // ---- layer 1: 4 chains of 2 ----
        f32x16 acc1[4];
#pragma unroll
        for (int mt = 0; mt < 4; ++mt) {
            f32x16 c = __builtin_amdgcn_mfma_f32_32x32x16_bf16(a1f[mt][0], g0, Z16, 0, 0, 0);
            acc1[mt]  = __builtin_amdgcn_mfma_f32_32x32x16_bf16(a1f[mt][1], g1, c, 0, 0, 0);
        }

        // ---- pack h1 -> B-frags (pi-mapped: frag kt = acc1[kt>>1] regs 8*(kt&1)..+7) ----
        bf16x8 hb[8];
#pragma unroll
        for (int kt = 0; kt < 8; ++kt) {
            const int r0 = 8 * (kt & 1);
            const f32x16 A = acc1[kt >> 1];
            u32x4 u;
            u[0] = cvtpk_relu(A[r0 + 0], A[r0 + 1]);
            u[1] = cvtpk_relu(A[r0 + 2], A[r0 + 3]);
            u[2] = cvtpk_relu(A[r0 + 4], A[r0 + 5]);
            u[3] = cvtpk_relu(A[r0 + 6], A[r0 + 7]);
            hb[kt] = __builtin_bit_cast(bf16x8, u);
        }

        // ---- layer 2: 4 chains of 9 (bias tile + 8 K-tiles), R0-style ct-outer ----
        f32x16 acc2[4];
#pragma unroll
        for (int mt = 0; mt < 4; ++mt) {
            f32x16 c = __builtin_amdgcn_mfma_f32_32x32x16_bf16(a2b[mt], fbias, Z16, 0, 0, 0);
#pragma unroll
            for (int kt = 0; kt < 8; ++kt)
                c = __builtin_amdgcn_mfma_f32_32x32x16_bf16(a2f[mt][kt], hb[kt], c, 0, 0, 0);
            acc2[mt] = c;
        }

        // ---- pack h2 -> B-frags (same pi) ----
        bf16x8 gb[8];
#pragma unroll
        for (int kt = 0; kt < 8; ++kt) {
            const int r0 = 8 * (kt & 1);
            const f32x16 A = acc2[kt >> 1];
            u32x4 u;
            u[0] = cvtpk_relu(A[r0 + 0], A[r0 + 1]);
            u[1] = cvtpk_relu(A[r0 + 2], A[r0 + 3]);
            u[2] = cvtpk_relu(A[r0 + 4], A[r0 + 5]);
            u[3] = cvtpk_relu(A[r0 + 6], A[r0 + 7]);
            gb[kt] = __builtin_bit_cast(bf16x8, u);
        }

        // ---- layer 3: one chain of 8, C-in = b3 ----
        f32x16 acc3 = b3c;
#pragma unroll
        for (int kt = 0; kt < 8; ++kt)
            acc3 = __builtin_amdgcn_mfma_f32_32x32x16_bf16(a3f[kt], gb[kt], acc3, 0, 0, 0);

        // ---- V partial + X update (z regs 0..7 = dims {0..3,8..11}+4hi) ----
#pragma unroll
        for (int r = 0; r < 4; ++r) {
            float z  = acc3[r];
            float wn = sqdt * eA0[r];
            vacc = fmaf(z, wn, fmaf(0.01f * z, z, vacc));   // z*wn + dt/2*z^2
        }
#pragma unroll
        for (int r = 0; r < 4; ++r) {
            float z  = acc3[4 + r];
            float wn = sqdt * eB0[r];
            vacc = fmaf(z, wn, fmaf(0.01f * z, z, vacc));
        }
#pragma unroll
        for (int r = 0; r < 4; ++r) {
            xA[r] = fmaf(xA[r], 0.98f, sqdt * eA0[r]);
            xB[r] = fmaf(xB[r], 0.98f, sqdt * eB0[r]);
        }

        eA0 = eA1; eB0 = eB1;
        t += dt;
    }

    // ---- per-particle V within this wave: combine the two hi halves ----
    vacc += __shfl_xor(vacc, 32);

    // ---- combine the two time-halves ----
    __shared__ float vsh[32];
    if (half == 0 && hi == 0) vsh[n] = vacc;
    __syncthreads();
    if (half == 1) {
        *(f32x4*)&out[gr * D_ + 4 * hi] = xA;              // final X (step 50)
        *(f32x4*)&out[gr * D_ + 8 + 4 * hi] = xB;
        if (hi == 0) out[N_ * D_ + gr] = V0[gr] + vsh[n] + vacc;
    }
}

extern "C" void kernel_launch(void* const* d_in, const int* in_sizes, int n_in,
                              void* d_out, int out_size, void* d_ws, size_t ws_size,
                              hipStream_t stream)
{
    const float* X0 = (const float*)d_in[0];
    const float* V0 = (const float*)d_in[1];
    const float* Y  = (const float*)d_in[2];
    const float* nz = (const float*)d_in[3];
    const float* W1 = (const float*)d_in[4];
    const float* b1 = (const float*)d_in[5];
    const float* W2 = (const float*)d_in[6];
    const float* b2 = (const float*)d_in[7];
    const float* W3 = (const float*)d_in[8];
    const float* b3 = (const float*)d_in[9];
    float* out = (float*)d_out;

    sde_fused<<<N_ / 32, 128, 0, stream>>>(X0, V0, Y, nz, W1, b1, W2, b2, W3, b3, out);
}

// Round 12
// 152.027 us; speedup vs baseline: 1.1335x; 1.0274x over previous
//
#include <hip/hip_runtime.h>

typedef __bf16   bf16x8 __attribute__((ext_vector_type(8)));
typedef float    f32x4  __attribute__((ext_vector_type(4)));
typedef float    f32x2  __attribute__((ext_vector_type(2)));
typedef uint32_t u32x4  __attribute__((ext_vector_type(4)));

constexpr int N_ = 16384;
constexpr int D_ = 16;
constexpr int P_ = 8;
constexpr int H_ = 128;
constexpr int M_ = 50;

// prologue-only pack (round-half-up; matches all passing rounds)
__device__ __forceinline__ uint32_t pk_bf16(float a, float b) {
    uint32_t ua = __builtin_bit_cast(uint32_t, a) + 0x8000u;
    uint32_t ub = __builtin_bit_cast(uint32_t, b) + 0x8000u;
    return __builtin_amdgcn_perm(ub, ua, 0x07060302u);   // low=a, high=b
}
// in-loop pack (RNE; validated R7/R8/R11/R12/R14)
__device__ __forceinline__ uint32_t cvtpk(float a, float b) {
    uint32_t r;
    asm("v_cvt_pk_bf16_f32 %0, %1, %2" : "=v"(r) : "v"(a), "v"(b));
    return r;
}
__device__ __forceinline__ uint32_t cvtpk_relu(float a, float b) {
    return cvtpk(fmaxf(a, 0.0f), fmaxf(b, 0.0f));
}

// volatile 16B LDS reads: cannot be promoted across iterations (the R7/R9
// spill cause); compiler still inserts correct lgkmcnt. R12-proven.
__device__ __forceinline__ bf16x8 lds_ldv8(const void* p) {
    u32x4 v = *(volatile const u32x4*)p;
    return __builtin_bit_cast(bf16x8, v);
}
__device__ __forceinline__ f32x4 lds_ldvf(const void* p) {
    u32x4 v = *(volatile const u32x4*)p;
    return __builtin_bit_cast(f32x4, v);
}

// R15: clean 2-wave co-issue test. R12's failure is now explained as LDS
// SATURATION (32KB W2 per wave-step = 97 B/cyc of the 128 B/cyc/CU ceiling
// at 8 waves/CU -> all waves stalled on lgkmcnt), not absent co-issue.
// Fix: TWO TIME-STEPS PER ITERATION (R11-proven numerics) so each streamed
// W2 fragment feeds TWO independent MFMA chains -> 16KB/wave-step = 48 B/cyc
// (37% of LDS). W2 lives ONLY in LDS (the 128-reg hog gone -> real register
// headroom; R12-style simple double-buffer + volatile, no rings/asm — the
// R13 spill mode avoided). w1/w3/b3 resident; b2 C-in prefetched from LDS
// one ct ahead (broadcast read, conflict-free). Time-split 26/24 steps,
// ZERO in-loop barriers. Grid 1024 blocks x 128 thr = 2 waves/SIMD.
// GATES: (1) WRITE_SIZE ~1.1MB (no spill); (2) win -> 32-42 us; (3) no-spill
// but flat -> co-issue definitively absent -> declare roofline next round.
__global__ __launch_bounds__(128, 2)
void sde_fused(const float* __restrict__ X0,
               const float* __restrict__ V0,
               const float* __restrict__ Yobs,
               const float* __restrict__ noise,
               const float* __restrict__ W1, const float* __restrict__ b1,
               const float* __restrict__ W2, const float* __restrict__ b2,
               const float* __restrict__ W3, const float* __restrict__ b3,
               float* __restrict__ out)
{
    const int tid  = threadIdx.x;
    const int lane = tid & 63;
    const int half = tid >> 6;           // 0: steps 0..25, 1: steps 26..49
    const int n    = lane & 15;
    const int q    = lane >> 4;
    const int gr   = blockIdx.x * 16 + n;

    const float dt   = 0.02f;
    const float sqdt = 0.1414213562373095f;

    __shared__ bf16x8 w2lds[8][4][64];   // 32 KB: per-lane A-frags of W2
    __shared__ float  b2lds[H_];         // 512 B
    __shared__ float  vpart[16];

    // ---- stage W2 to LDS (each wave its 4 ct tiles) + b2 ----
#pragma unroll
    for (int cc = 0; cc < 4; ++cc) {
        const int ct = half * 4 + cc;
#pragma unroll
        for (int kt = 0; kt < 4; ++kt) {
            u32x4 u;
#pragma unroll
            for (int w = 0; w < 4; ++w) {
                int h0 = (kt * 2 + (w >> 1)) * 16 + q * 4 + (w & 1) * 2;
                u[w] = pk_bf16(W2[h0 * H_ + ct * 16 + n],
                               W2[(h0 + 1) * H_ + ct * 16 + n]);
            }
            w2lds[ct][kt][lane] = __builtin_bit_cast(bf16x8, u);
        }
    }
    if (half == 0 && lane < 32)
        *(f32x4*)&b2lds[lane * 4] = *(const f32x4*)&b2[lane * 4];

    // ---- register-resident small operands ----
    bf16x8 w1f[8];
#pragma unroll
    for (int ct = 0; ct < 8; ++ct) {
        u32x4 u;
        u[0] = pk_bf16(W1[(1 + q * 4 + 0) * H_ + ct * 16 + n],
                       W1[(1 + q * 4 + 1) * H_ + ct * 16 + n]);
        u[1] = pk_bf16(W1[(1 + q * 4 + 2) * H_ + ct * 16 + n],
                       W1[(1 + q * 4 + 3) * H_ + ct * 16 + n]);
        u[2] = pk_bf16(W1[(17 + q * 2 + 0) * H_ + ct * 16 + n],
                       W1[(17 + q * 2 + 1) * H_ + ct * 16 + n]);
        u[3] = (q == 0) ? pk_bf16(b1[ct * 16 + n], W1[ct * 16 + n]) : 0u;
        w1f[ct] = __builtin_bit_cast(bf16x8, u);
    }
    bf16x8 w3f[4];
#pragma unroll
    for (int kt = 0; kt < 4; ++kt) {
        u32x4 u;
#pragma unroll
        for (int w = 0; w < 4; ++w) {
            int h0 = (kt * 2 + (w >> 1)) * 16 + q * 4 + (w & 1) * 2;
            u[w] = pk_bf16(W3[h0 * D_ + n], W3[(h0 + 1) * D_ + n]);
        }
        w3f[kt] = __builtin_bit_cast(bf16x8, u);
    }
    f32x4 b3r = *(const f32x4*)&b3[q * 4];

    __syncthreads();   // LDS ready (only barrier before the end)

    // ---- state ----
    f32x4 x = *(const f32x4*)&X0[gr * D_ + q * 4];
    f32x2 y2 = *(const f32x2*)&Yobs[gr * P_ + q * 2];
    const uint32_t yw = pk_bf16(y2[0], y2[1]);
    const float* npb = noise + (size_t)gr * D_ + q * 4;

    // ---- wave 1: bit-exact X-recurrence replay through steps 0..25 ----
    if (half == 1) {
#pragma unroll 2
        for (int m = 0; m < 26; ++m) {
            f32x4 e = *(const f32x4*)(npb + (size_t)m * N_ * D_);
#pragma unroll
            for (int r = 0; r < 4; ++r)
                x[r] = fmaf(x[r], 0.98f, sqdt * e[r]);
        }
    }

    const int start  = half ? 26 : 0;
    const int npairs = half ? 12 : 13;

    f32x4 e0 = *(const f32x4*)(npb + (size_t)start * N_ * D_);
    f32x4 e1 = *(const f32x4*)(npb + (size_t)(start + 1) * N_ * D_);
    float vaccA = 0.0f, vaccB = 0.0f;

#pragma unroll 1
    for (int p = 0; p < npairs; ++p) {
        const int mA = start + 2 * p;
        const int p2 = (mA + 2 < M_) ? (mA + 2) : (M_ - 1);
        const int p3 = (mA + 3 < M_) ? (mA + 3) : (M_ - 1);
        f32x4 e2 = *(const f32x4*)(npb + (size_t)p2 * N_ * D_);
        f32x4 e3 = *(const f32x4*)(npb + (size_t)p3 * N_ * D_);

        const float tA = (float)mA * dt;
        const float tB = (float)(mA + 1) * dt;

        // step B's X (depends only on x, e0 — R11-proven)
        f32x4 xB;
#pragma unroll
        for (int r = 0; r < 4; ++r) xB[r] = fmaf(x[r], 0.98f, sqdt * e0[r]);

        // ---- prefetch ct0 W2 frags + ct0 C-in (covered by L1 below) ----
        bf16x8 wb[2][4];
#pragma unroll
        for (int kt = 0; kt < 4; ++kt) wb[0][kt] = lds_ldv8(&w2lds[0][kt][lane]);
        f32x4 cb[2];
        cb[0] = lds_ldvf(&b2lds[q * 4]);

        // ---- L1 B fragments ----
        u32x4 auA;
        auA[0] = cvtpk(x[0], x[1]);
        auA[1] = cvtpk(x[2], x[3]);
        auA[2] = yw;
        auA[3] = (q == 0) ? cvtpk(1.0f, tA) : 0u;
        bf16x8 a0A = __builtin_bit_cast(bf16x8, auA);
        u32x4 auB;
        auB[0] = cvtpk(xB[0], xB[1]);
        auB[1] = cvtpk(xB[2], xB[3]);
        auB[2] = yw;
        auB[3] = (q == 0) ? cvtpk(1.0f, tB) : 0u;
        bf16x8 a0B = __builtin_bit_cast(bf16x8, auB);

        // ---- layer 1, both streams (R0 form each) ----
        f32x4 h1cA[8];
#pragma unroll
        for (int ct = 0; ct < 8; ++ct)
            h1cA[ct] = __builtin_amdgcn_mfma_f32_16x16x32_bf16(
                w1f[ct], a0A, (f32x4){0.f, 0.f, 0.f, 0.f}, 0, 0, 0);
        bf16x8 h1bA[4];
#pragma unroll
        for (int kt = 0; kt < 4; ++kt) {
            u32x4 u;
            u[0] = cvtpk_relu(h1cA[2 * kt][0], h1cA[2 * kt][1]);
            u[1] = cvtpk_relu(h1cA[2 * kt][2], h1cA[2 * kt][3]);
            u[2] = cvtpk_relu(h1cA[2 * kt + 1][0], h1cA[2 * kt + 1][1]);
            u[3] = cvtpk_relu(h1cA[2 * kt + 1][2], h1cA[2 * kt + 1][3]);
            h1bA[kt] = __builtin_bit_cast(bf16x8, u);
        }
        f32x4 h1cB[8];
#pragma unroll
        for (int ct = 0; ct < 8; ++ct)
            h1cB[ct] = __builtin_amdgcn_mfma_f32_16x16x32_bf16(
                w1f[ct], a0B, (f32x4){0.f, 0.f, 0.f, 0.f}, 0, 0, 0);
        bf16x8 h1bB[4];
#pragma unroll
        for (int kt = 0; kt < 4; ++kt) {
            u32x4 u;
            u[0] = cvtpk_relu(h1cB[2 * kt][0], h1cB[2 * kt][1]);
            u[1] = cvtpk_relu(h1cB[2 * kt][2], h1cB[2 * kt][3]);
            u[2] = cvtpk_relu(h1cB[2 * kt + 1][0], h1cB[2 * kt + 1][1]);
            u[3] = cvtpk_relu(h1cB[2 * kt + 1][2], h1cB[2 * kt + 1][3]);
            h1bB[kt] = __builtin_bit_cast(bf16x8, u);
        }

        // ---- layer 2: stream W2 once, feed BOTH steps' chains ----
        bf16x8 h2bA[4], h2bB[4];
        f32x4 hpA, hpB;
#pragma unroll
        for (int ct = 0; ct < 8; ++ct) {
            if (ct < 7) {
#pragma unroll
                for (int kt = 0; kt < 4; ++kt)
                    wb[(ct + 1) & 1][kt] = lds_ldv8(&w2lds[ct + 1][kt][lane]);
                cb[(ct + 1) & 1] = lds_ldvf(&b2lds[(ct + 1) * 16 + q * 4]);
            }
            f32x4 cA = cb[ct & 1];
            f32x4 cB = cA;
#pragma unroll
            for (int kt = 0; kt < 4; ++kt)
                cA = __builtin_amdgcn_mfma_f32_16x16x32_bf16(
                    wb[ct & 1][kt], h1bA[kt], cA, 0, 0, 0);
#pragma unroll
            for (int kt = 0; kt < 4; ++kt)
                cB = __builtin_amdgcn_mfma_f32_16x16x32_bf16(
                    wb[ct & 1][kt], h1bB[kt], cB, 0, 0, 0);
            if ((ct & 1) == 0) {
                hpA = cA; hpB = cB;
            } else {
                u32x4 uA;
                uA[0] = cvtpk_relu(hpA[0], hpA[1]);
                uA[1] = cvtpk_relu(hpA[2], hpA[3]);
                uA[2] = cvtpk_relu(cA[0], cA[1]);
                uA[3] = cvtpk_relu(cA[2], cA[3]);
                h2bA[ct >> 1] = __builtin_bit_cast(bf16x8, uA);
                u32x4 uB;
                uB[0] = cvtpk_relu(hpB[0], hpB[1]);
                uB[1] = cvtpk_relu(hpB[2], hpB[3]);
                uB[2] = cvtpk_relu(cB[0], cB[1]);
                uB[3] = cvtpk_relu(cB[2], cB[3]);
                h2bB[ct >> 1] = __builtin_bit_cast(bf16x8, uB);
            }
        }

        // ---- layer 3, both streams (R0 form) ----
        f32x4 zaA = __builtin_amdgcn_mfma_f32_16x16x32_bf16(w3f[0], h2bA[0], b3r, 0, 0, 0);
        zaA = __builtin_amdgcn_mfma_f32_16x16x32_bf16(w3f[1], h2bA[1], zaA, 0, 0, 0);
        f32x4 zbA = __builtin_amdgcn_mfma_f32_16x16x32_bf16(
            w3f[2], h2bA[2], (f32x4){0.f, 0.f, 0.f, 0.f}, 0, 0, 0);
        zbA = __builtin_amdgcn_mfma_f32_16x16x32_bf16(w3f[3], h2bA[3], zbA, 0, 0, 0);
        f32x4 zaB = __builtin_amdgcn_mfma_f32_16x16x32_bf16(w3f[0], h2bB[0], b3r, 0, 0, 0);
        zaB = __builtin_amdgcn_mfma_f32_16x16x32_bf16(w3f[1], h2bB[1], zaB, 0, 0, 0);
        f32x4 zbB = __builtin_amdgcn_mfma_f32_16x16x32_bf16(
            w3f[2], h2bB[2], (f32x4){0.f, 0.f, 0.f, 0.f}, 0, 0, 0);
        zbB = __builtin_amdgcn_mfma_f32_16x16x32_bf16(w3f[3], h2bB[3], zbB, 0, 0, 0);

        // ---- V partials + advance X through both steps ----
#pragma unroll
        for (int r = 0; r < 4; ++r) {
            float zA  = zaA[r] + zbA[r];
            float wnA = sqdt * e0[r];
            vaccA = fmaf(zA, wnA, fmaf(0.01f * zA, zA, vaccA));
            float zB  = zaB[r] + zbB[r];
            float wnB = sqdt * e1[r];
            vaccB = fmaf(zB, wnB, fmaf(0.01f * zB, zB, vaccB));
            x[r] = fmaf(xB[r], 0.98f, wnB);                 // x after step mA+1
        }

        e0 = e2; e1 = e3;
    }

    // ---- V reduction across the 4 q-groups within each wave ----
    float part = vaccA + vaccB;
    part += __shfl_xor(part, 16);
    part += __shfl_xor(part, 32);

    // ---- combine the two time-halves ----
    if (half == 0 && q == 0) vpart[n] = part;
    __syncthreads();
    if (half == 1) {
        *(f32x4*)&out[gr * D_ + q * 4] = x;                 // final X (step 50)
        if (q == 0) out[N_ * D_ + gr] = V0[gr] + vpart[n] + part;
    }
}

extern "C" void kernel_launch(void* const* d_in, const int* in_sizes, int n_in,
                              void* d_out, int out_size, void* d_ws, size_t ws_size,
                              hipStream_t stream)
{
    const float* X0 = (const float*)d_in[0];
    const float* V0 = (const float*)d_in[1];
    const float* Y  = (const float*)d_in[2];
    const float* nz = (const float*)d_in[3];
    const float* W1 = (const float*)d_in[4];
    const float* b1 = (const float*)d_in[5];
    const float* W2 = (const float*)d_in[6];
    const float* b2 = (const float*)d_in[7];
    const float* W3 = (const float*)d_in[8];
    const float* b3 = (const float*)d_in[9];
    float* out = (float*)d_out;

    sde_fused<<<N_ / 16, 128, 0, stream>>>(X0, V0, Y, nz, W1, b1, W2, b2, W3, b3, out);
}